// Round 1
// baseline (372.273 us; speedup 1.0000x reference)
//
#include <hip/hip_runtime.h>
#include <hip/hip_bf16.h>
#include <math.h>

typedef unsigned short u16;
typedef u16 u16x8 __attribute__((ext_vector_type(8)));
typedef __bf16 bf16x8 __attribute__((ext_vector_type(8)));
typedef float f32x4 __attribute__((ext_vector_type(4)));

#define MODE_BF16 0
#define MODE_GELU 1
#define MODE_RESF32 2

__device__ __forceinline__ u16 f2bf(float f) {
    unsigned int u = __float_as_uint(f);
    u = (u + 0x7fffu + ((u >> 16) & 1u)) >> 16;
    return (u16)u;
}

// ---------------------------------------------------------------------------
// Weight transpose + fp32->bf16 convert:  W[K][N] -> WT[N][K] (bf16)
// ---------------------------------------------------------------------------
__global__ __launch_bounds__(256) void wtrans_kernel(
    const float* __restrict__ W, u16* __restrict__ WT, int Krows, int Ncols)
{
    __shared__ float tile[32][33];
    const int k0 = blockIdx.x * 32, n0 = blockIdx.y * 32;
    const int tx = threadIdx.x & 31, ty = threadIdx.x >> 5;  // ty 0..7
#pragma unroll
    for (int j = 0; j < 32; j += 8)
        tile[ty + j][tx] = W[(size_t)(k0 + ty + j) * Ncols + n0 + tx];
    __syncthreads();
#pragma unroll
    for (int j = 0; j < 32; j += 8)
        WT[(size_t)(n0 + ty + j) * Krows + k0 + tx] = f2bf(tile[tx][ty + j]);
}

// ---------------------------------------------------------------------------
// LayerNorm (ddof=1, divide by std+eps, scalar gamma/beta), fp32 -> bf16
// ---------------------------------------------------------------------------
__global__ __launch_bounds__(256) void ln_kernel(
    const float* __restrict__ X, u16* __restrict__ Y,
    const float* __restrict__ gp, const float* __restrict__ bp)
{
    __shared__ float sbuf[8];
    const int row = blockIdx.x, t = threadIdx.x;
    const float* xr = X + (size_t)row * 768;
    float v0 = xr[t], v1 = xr[t + 256], v2 = xr[t + 512];
    float s = v0 + v1 + v2;
    float q = v0 * v0 + v1 * v1 + v2 * v2;
#pragma unroll
    for (int m = 1; m < 64; m <<= 1) {
        s += __shfl_xor(s, m, 64);
        q += __shfl_xor(q, m, 64);
    }
    const int wave = t >> 6, lane = t & 63;
    if (lane == 0) { sbuf[wave] = s; sbuf[4 + wave] = q; }
    __syncthreads();
    s = sbuf[0] + sbuf[1] + sbuf[2] + sbuf[3];
    q = sbuf[4] + sbuf[5] + sbuf[6] + sbuf[7];
    const float mean = s * (1.0f / 768.0f);
    float ssd = q - 768.0f * mean * mean;
    ssd = fmaxf(ssd, 0.0f);
    const float stdv = sqrtf(ssd * (1.0f / 767.0f));
    const float scale = gp[0] / (stdv + 1e-5f);
    const float beta = bp[0];
    u16* yr = Y + (size_t)row * 768;
    yr[t]       = f2bf((v0 - mean) * scale + beta);
    yr[t + 256] = f2bf((v1 - mean) * scale + beta);
    yr[t + 512] = f2bf((v2 - mean) * scale + beta);
}

// ---------------------------------------------------------------------------
// GEMM: C[M][N] = A[M][K](bf16) @ BT[N][K]^T(bf16) + bias, fused epilogue.
// 128x128 tile, BK=64, 256 threads = 4 waves (2x2), each wave 64x64.
// ---------------------------------------------------------------------------
template <int MODE>
__global__ __launch_bounds__(256) void gemm_kernel(
    const u16* __restrict__ A, const u16* __restrict__ BT,
    const float* __restrict__ bias, const float* __restrict__ res,
    void* __restrict__ outp, int M, int N, int K)
{
    __shared__ u16 As[128][72];
    __shared__ u16 Bs[128][72];
    const int t = threadIdx.x;
    const int lane = t & 63, wave = t >> 6;
    const int wr = wave >> 1, wc = wave & 1;
    const int g = lane >> 4, c = lane & 15;
    const int bm = blockIdx.x, bn = blockIdx.y;

    const int srow = t >> 3;           // staging row base (0..31)
    const int scol = (t & 7) * 8;      // staging col (elements)
    const u16* Ag = A + (size_t)(bm * 128 + srow) * K + scol;
    const u16* Bg = BT + (size_t)(bn * 128 + srow) * K + scol;

    f32x4 acc[4][4] = {};

    for (int k0 = 0; k0 < K; k0 += 64) {
        u16x8 ra[4], rb[4];
#pragma unroll
        for (int j = 0; j < 4; j++) {
            ra[j] = *(const u16x8*)(Ag + (size_t)(32 * j) * K + k0);
            rb[j] = *(const u16x8*)(Bg + (size_t)(32 * j) * K + k0);
        }
        __syncthreads();
#pragma unroll
        for (int j = 0; j < 4; j++) {
            *(u16x8*)&As[srow + 32 * j][scol] = ra[j];
            *(u16x8*)&Bs[srow + 32 * j][scol] = rb[j];
        }
        __syncthreads();
#pragma unroll
        for (int kk = 0; kk < 2; kk++) {
            bf16x8 af[4], bfr[4];
#pragma unroll
            for (int m = 0; m < 4; m++)
                af[m] = *(const bf16x8*)&As[wr * 64 + m * 16 + c][kk * 32 + g * 8];
#pragma unroll
            for (int n = 0; n < 4; n++)
                bfr[n] = *(const bf16x8*)&Bs[wc * 64 + n * 16 + c][kk * 32 + g * 8];
#pragma unroll
            for (int m = 0; m < 4; m++)
#pragma unroll
                for (int n = 0; n < 4; n++)
                    acc[m][n] = __builtin_amdgcn_mfma_f32_16x16x32_bf16(
                        af[m], bfr[n], acc[m][n], 0, 0, 0);
        }
    }

#pragma unroll
    for (int m = 0; m < 4; m++) {
        const int row = bm * 128 + wr * 64 + m * 16 + 4 * g;
#pragma unroll
        for (int n = 0; n < 4; n++) {
            const int col = bn * 128 + wc * 64 + n * 16 + c;
            const float bv = bias[col];
#pragma unroll
            for (int i = 0; i < 4; i++) {
                float v = acc[m][n][i] + bv;
                const size_t idx = (size_t)(row + i) * N + col;
                if constexpr (MODE == MODE_GELU) {
                    v = 0.5f * v * (1.0f + erff(v * 0.70710678118654752f));
                    ((u16*)outp)[idx] = f2bf(v);
                } else if constexpr (MODE == MODE_BF16) {
                    ((u16*)outp)[idx] = f2bf(v);
                } else {
                    ((float*)outp)[idx] = v + res[idx];
                }
            }
        }
    }
}

// ---------------------------------------------------------------------------
// Flash attention: grid (16 q-tiles, 96 b*h), 256 thr = 4 waves x 16 q-rows.
// KV tile 64.  scores = Q K^T / 8, online softmax, out = P V.
// ---------------------------------------------------------------------------
__global__ __launch_bounds__(256) void attn_kernel(
    const u16* __restrict__ Q, const u16* __restrict__ Kg,
    const u16* __restrict__ V, u16* __restrict__ O)
{
    __shared__ u16 Vt[64][72];       // V^T tile: [d][kv]
    __shared__ u16 Pl[4][16][72];    // per-wave P: [q][kv]
    const int t = threadIdx.x, lane = t & 63, wave = t >> 6;
    const int g = lane >> 4, c = lane & 15;
    const int qt = blockIdx.x, bh = blockIdx.y;
    const int b = bh / 12, h = bh % 12;
    const size_t rowb = (size_t)b * 1024;
    const int q0 = qt * 64 + wave * 16;

    bf16x8 qf[2];
    {
        const u16* qp = Q + (rowb + q0 + c) * 768 + h * 64 + g * 8;
        qf[0] = *(const bf16x8*)qp;
        qf[1] = *(const bf16x8*)(qp + 32);
    }

    float m_run[4] = {-1e30f, -1e30f, -1e30f, -1e30f};
    float l_run[4] = {0.f, 0.f, 0.f, 0.f};
    f32x4 o_acc[4] = {};

    const int vkv = t >> 2, vds = (t & 3) * 16;
    const u16* vp = V + (rowb + vkv) * 768 + h * 64 + vds;

    for (int kvt = 0; kvt < 16; ++kvt) {
        const int kv0 = kvt * 64;
        u16x8 va0 = *(const u16x8*)(vp + (size_t)kv0 * 768);
        u16x8 va1 = *(const u16x8*)(vp + (size_t)kv0 * 768 + 8);
        __syncthreads();  // previous PV reads done before overwrite
#pragma unroll
        for (int j = 0; j < 8; j++) {
            Vt[vds + j][vkv]     = va0[j];
            Vt[vds + 8 + j][vkv] = va1[j];
        }

        // scores S[16 q][64 kv]
        f32x4 s[4] = {};
#pragma unroll
        for (int n = 0; n < 4; n++) {
            const u16* kp = Kg + (rowb + kv0 + n * 16 + c) * 768 + h * 64 + g * 8;
            bf16x8 kf0 = *(const bf16x8*)kp;
            bf16x8 kf1 = *(const bf16x8*)(kp + 32);
            s[n] = __builtin_amdgcn_mfma_f32_16x16x32_bf16(qf[0], kf0, s[n], 0, 0, 0);
            s[n] = __builtin_amdgcn_mfma_f32_16x16x32_bf16(qf[1], kf1, s[n], 0, 0, 0);
        }

        // online softmax (row r = 4*g+i, reduce across the 16 c-lanes)
        float resc[4];
#pragma unroll
        for (int i = 0; i < 4; i++) {
            float mx = fmaxf(fmaxf(s[0][i], s[1][i]), fmaxf(s[2][i], s[3][i]));
#pragma unroll
            for (int msk = 1; msk < 16; msk <<= 1)
                mx = fmaxf(mx, __shfl_xor(mx, msk, 64));
            mx *= 0.125f;
            const float mnew = fmaxf(m_run[i], mx);
            resc[i] = __expf(m_run[i] - mnew);
            m_run[i] = mnew;
            float rs = 0.f;
#pragma unroll
            for (int n = 0; n < 4; n++) {
                const float p = __expf(s[n][i] * 0.125f - mnew);
                rs += p;
                Pl[wave][4 * g + i][n * 16 + c] = f2bf(p);
            }
#pragma unroll
            for (int msk = 1; msk < 16; msk <<= 1)
                rs += __shfl_xor(rs, msk, 64);
            l_run[i] = l_run[i] * resc[i] + rs;
            o_acc[0][i] *= resc[i];
            o_acc[1][i] *= resc[i];
            o_acc[2][i] *= resc[i];
            o_acc[3][i] *= resc[i];
        }
        __syncthreads();  // Vt staged (Pl is wave-private; barrier covers both)

        bf16x8 pa0 = *(const bf16x8*)&Pl[wave][c][g * 8];
        bf16x8 pa1 = *(const bf16x8*)&Pl[wave][c][32 + g * 8];
#pragma unroll
        for (int n = 0; n < 4; n++) {
            bf16x8 vf0 = *(const bf16x8*)&Vt[n * 16 + c][g * 8];
            bf16x8 vf1 = *(const bf16x8*)&Vt[n * 16 + c][32 + g * 8];
            o_acc[n] = __builtin_amdgcn_mfma_f32_16x16x32_bf16(pa0, vf0, o_acc[n], 0, 0, 0);
            o_acc[n] = __builtin_amdgcn_mfma_f32_16x16x32_bf16(pa1, vf1, o_acc[n], 0, 0, 0);
        }
    }

#pragma unroll
    for (int i = 0; i < 4; i++) {
        const float inv = 1.0f / l_run[i];
        const size_t row = rowb + q0 + 4 * g + i;
#pragma unroll
        for (int n = 0; n < 4; n++)
            O[row * 768 + h * 64 + n * 16 + c] = f2bf(o_acc[n][i] * inv);
    }
}

// ---------------------------------------------------------------------------
// Launch
// ---------------------------------------------------------------------------
extern "C" void kernel_launch(void* const* d_in, const int* in_sizes, int n_in,
                              void* d_out, int out_size, void* d_ws, size_t ws_size,
                              hipStream_t stream)
{
    const float* x   = (const float*)d_in[0];
    const float* wq  = (const float*)d_in[1];
    const float* bq  = (const float*)d_in[2];
    const float* wk  = (const float*)d_in[3];
    const float* bk  = (const float*)d_in[4];
    const float* wv  = (const float*)d_in[5];
    const float* bv  = (const float*)d_in[6];
    const float* wo  = (const float*)d_in[7];
    const float* bo  = (const float*)d_in[8];
    const float* w1  = (const float*)d_in[9];
    const float* b1  = (const float*)d_in[10];
    const float* w2  = (const float*)d_in[11];
    const float* b2  = (const float*)d_in[12];
    const float* g1  = (const float*)d_in[13];
    const float* be1 = (const float*)d_in[14];
    const float* g2  = (const float*)d_in[15];
    const float* be2 = (const float*)d_in[16];

    char* ws = (char*)d_ws;
    constexpr size_t SZ_W768 = (size_t)768 * 768 * 2;     // bf16 bytes
    constexpr size_t SZ_WFF  = (size_t)768 * 3072 * 2;
    constexpr size_t SZ_TD   = (size_t)8192 * 768 * 2;    // token x d_model bf16
    constexpr size_t O_WQ = 0;
    constexpr size_t O_WK = O_WQ + SZ_W768;
    constexpr size_t O_WV = O_WK + SZ_W768;
    constexpr size_t O_WO = O_WV + SZ_W768;
    constexpr size_t O_W1 = O_WO + SZ_W768;
    constexpr size_t O_W2 = O_W1 + SZ_WFF;
    constexpr size_t O_XLN = O_W2 + SZ_WFF;
    constexpr size_t O_Q = O_XLN + SZ_TD;
    constexpr size_t O_K = O_Q + SZ_TD;
    constexpr size_t O_V = O_K + SZ_TD;
    constexpr size_t O_ATTN = O_V + SZ_TD;
    constexpr size_t O_H = O_ATTN + SZ_TD;                // fp32
    constexpr size_t O_F = O_XLN;                          // reuse xln..V (50.3MB)
    constexpr size_t O_HLN = O_ATTN;                       // reuse attn

    u16* wqT = (u16*)(ws + O_WQ);
    u16* wkT = (u16*)(ws + O_WK);
    u16* wvT = (u16*)(ws + O_WV);
    u16* woT = (u16*)(ws + O_WO);
    u16* w1T = (u16*)(ws + O_W1);
    u16* w2T = (u16*)(ws + O_W2);
    u16* xln = (u16*)(ws + O_XLN);
    u16* Qb  = (u16*)(ws + O_Q);
    u16* Kb  = (u16*)(ws + O_K);
    u16* Vb  = (u16*)(ws + O_V);
    u16* attnb = (u16*)(ws + O_ATTN);
    float* h = (float*)(ws + O_H);
    u16* fb  = (u16*)(ws + O_F);
    u16* hln = (u16*)(ws + O_HLN);

    dim3 blk(256);
    // weight transposes (W[K][N] -> WT[N][K] bf16)
    wtrans_kernel<<<dim3(24, 24), blk, 0, stream>>>(wq, wqT, 768, 768);
    wtrans_kernel<<<dim3(24, 24), blk, 0, stream>>>(wk, wkT, 768, 768);
    wtrans_kernel<<<dim3(24, 24), blk, 0, stream>>>(wv, wvT, 768, 768);
    wtrans_kernel<<<dim3(24, 24), blk, 0, stream>>>(wo, woT, 768, 768);
    wtrans_kernel<<<dim3(24, 96), blk, 0, stream>>>(w1, w1T, 768, 3072);
    wtrans_kernel<<<dim3(96, 24), blk, 0, stream>>>(w2, w2T, 3072, 768);

    // LN1
    ln_kernel<<<8192, blk, 0, stream>>>(x, xln, g1, be1);
    // Q,K,V projections
    gemm_kernel<MODE_BF16><<<dim3(64, 6), blk, 0, stream>>>(xln, wqT, bq, nullptr, Qb, 8192, 768, 768);
    gemm_kernel<MODE_BF16><<<dim3(64, 6), blk, 0, stream>>>(xln, wkT, bk, nullptr, Kb, 8192, 768, 768);
    gemm_kernel<MODE_BF16><<<dim3(64, 6), blk, 0, stream>>>(xln, wvT, bv, nullptr, Vb, 8192, 768, 768);
    // attention
    attn_kernel<<<dim3(16, 96), blk, 0, stream>>>(Qb, Kb, Vb, attnb);
    // output projection + residual -> h (fp32)
    gemm_kernel<MODE_RESF32><<<dim3(64, 6), blk, 0, stream>>>(attnb, woT, bo, x, h, 8192, 768, 768);
    // LN2
    ln_kernel<<<8192, blk, 0, stream>>>(h, hln, g2, be2);
    // FFN1 + GELU
    gemm_kernel<MODE_GELU><<<dim3(64, 24), blk, 0, stream>>>(hln, w1T, b1, nullptr, fb, 8192, 3072, 768);
    // FFN2 + residual -> out (fp32)
    gemm_kernel<MODE_RESF32><<<dim3(64, 6), blk, 0, stream>>>(fb, w2T, b2, h, (float*)d_out, 8192, 768, 3072);
}